// Round 14
// baseline (562.214 us; speedup 1.0000x reference)
//
#include <hip/hip_runtime.h>
#include <hip/hip_bf16.h>

#define N_NODES 8192
#define CAP 128
#define XSTR 200   // bf16 elems per LDS x-row
#define FFSTR 193  // f32 elems per LDS feat-row
#define NBLK 512
#define SUPSZ (N_NODES * 64)   // ushorts per per-layer sup buffer (1 MB, bf16)
#define LEAF_BASE 16384        // int index of leaf-done flags in bar[]

typedef short s16x8 __attribute__((ext_vector_type(8)));
typedef float f32x4 __attribute__((ext_vector_type(4)));
typedef unsigned short u16x8 __attribute__((ext_vector_type(8)));

// ---------------------------------------------------------------------------
// sc1 (agent-scope) stores: producer data lands at the coherence point before
// the barrier; consumers use NORMAL cached loads (write-once buffers).
// ---------------------------------------------------------------------------
__device__ __forceinline__ void cstoref(float* p, float v) {
    __hip_atomic_store(p, v, __ATOMIC_RELAXED, __HIP_MEMORY_SCOPE_AGENT);
}
__device__ __forceinline__ void cstoreh(unsigned short* p, unsigned short v) {
    __hip_atomic_store(p, v, __ATOMIC_RELAXED, __HIP_MEMORY_SCOPE_AGENT);
}
__device__ __forceinline__ void cstorei(int* p, int v) {
    __hip_atomic_store(p, v, __ATOMIC_RELAXED, __HIP_MEMORY_SCOPE_AGENT);
}
__device__ __forceinline__ int cloadi(const int* p) {
    return __hip_atomic_load(p, __ATOMIC_RELAXED, __HIP_MEMORY_SCOPE_AGENT);
}
__device__ __forceinline__ float b2f(unsigned short u) {
    union { unsigned int i; float f; } c; c.i = ((unsigned int)u) << 16; return c.f;
}

// ---------------------------------------------------------------------------
// prep dispatch: blocks 0..2047 build the CSR (4 rows/block, wave-per-row,
// 8 x 16B independent loads in flight per lane, LDS-atomic compaction,
// coalesced writeback). Blocks 2048.. do the weight transform. At 8
// blocks/CU this scan is HBM-BW-bound (~50us) instead of the persistent
// kernel's 2-blocks/CU serialized stage->drain->process (~100-130us).
// Normal stores: the dispatch boundary makes results visible to 'layers'.
// ---------------------------------------------------------------------------
__global__ __launch_bounds__(256) void prep(
    const unsigned int* __restrict__ adj,
    const float* __restrict__ W1, const float* __restrict__ Wm,
    int* __restrict__ cnt, int* __restrict__ cols,
    unsigned short* __restrict__ Wt1, unsigned short* __restrict__ WtM)
{
    const int tid = threadIdx.x;
    if (blockIdx.x >= 2048) {
        int idx = (int)(blockIdx.x - 2048) * 256 + tid;
        if (idx >= 6144 + 55296) return;
        const float* src; unsigned short* dst; int KT, t, c, lane;
        if (idx < 6144) {
            KT = 8; src = W1; dst = Wt1;
            t = idx / 512; c = (idx >> 6) & 7; lane = idx & 63;
        } else {
            int r = idx - 6144;
            int mat = r / 4608;
            int rem = r % 4608;
            KT = 6; src = Wm + (size_t)mat * 36864; dst = WtM + (size_t)mat * 36864;
            t = rem / 384; c = (rem >> 6) % 6; lane = rem & 63;
        }
        int n = t * 16 + (lane & 15);
        int k0 = c * 32 + ((lane >> 4) << 3);
        u16x8 o;
#pragma unroll
        for (int j = 0; j < 8; ++j)
            o[j] = __bfloat16_as_ushort(__float2bfloat16(src[(size_t)(k0 + j) * 192 + n]));
        *reinterpret_cast<u16x8*>(dst + ((size_t)(t * KT + c) * 64 + lane) * 8) = o;
        return;
    }

    __shared__ int cntL[4];
    __shared__ int colsL[4][CAP];
    const int wave = tid >> 6;
    const int lane = tid & 63;
    const int row = (int)blockIdx.x * 4 + wave;
    if (lane == 0) cntL[wave] = 0;
    __syncthreads();

    const unsigned int* arow = adj + ((size_t)row << 13);
    for (int b = 0; b < 4; ++b) {
        uint4 v[8];
#pragma unroll
        for (int i = 0; i < 8; ++i) {
            int chunk = (b * 8 + i) * 64 + lane;
            v[i] = *reinterpret_cast<const uint4*>(arow + ((size_t)chunk << 2));
        }
#pragma unroll
        for (int i = 0; i < 8; ++i) {
            if ((v[i].x | v[i].y | v[i].z | v[i].w) == 0u) continue;
            int e0 = ((b * 8 + i) * 64 + lane) << 2;
            int loc[4]; int k = 0;
            if (v[i].x) loc[k++] = e0;
            if (v[i].y) loc[k++] = e0 + 1;
            if (v[i].z) loc[k++] = e0 + 2;
            if (v[i].w) loc[k++] = e0 + 3;
            int pos = atomicAdd(&cntL[wave], k);
            for (int j = 0; j < k; ++j)
                if (pos + j < CAP) colsL[wave][pos + j] = loc[j];
        }
    }
    __syncthreads();
    int n = cntL[wave]; if (n > CAP) n = CAP;
    if (lane == 0) cnt[row] = n;
    for (int j = lane; j < CAP; j += 64)
        cols[(size_t)row * CAP + j] = (j < n) ? colsL[wave][j] : 0;
}

// ---------------------------------------------------------------------------
// Hierarchical FLAG barrier (R12, best-measured class). Arrive = parallel sc1
// STORE to own flag line; 32 leaf pollers publish leaf-done; everyone polls
// only the 32 leaf-done lines (~1MB/round). ~8us/phase = detection + skew
// floor (R9-R12 all cluster here).
// ---------------------------------------------------------------------------
__device__ __forceinline__ void gbar_arrive(int* bar, int phase) {
    asm volatile("s_waitcnt vmcnt(0)" ::: "memory");
    __syncthreads();
    if (threadIdx.x == 0)
        cstorei(bar + blockIdx.x * 32, phase);
}
__device__ __forceinline__ void gbar_wait(int* bar, int phase) {
    const int tid = threadIdx.x;
    if (tid < 64) {
        if ((blockIdx.x & 15) == 0) {                 // leaf poller
            const int leaf = blockIdx.x >> 4;
            int rounds = 0;
            for (;;) {
                int v = (tid < 16) ? cloadi(bar + (leaf * 16 + tid) * 32)
                                   : 0x7fffffff;
#pragma unroll
                for (int off = 32; off > 0; off >>= 1)
                    v = min(v, __shfl_xor(v, off));
                if (v >= phase) break;
                __builtin_amdgcn_s_sleep(1);
                if (++rounds > (1 << 20)) break;      // failsafe: no hang
            }
            if (tid == 0) cstorei(bar + LEAF_BASE + leaf * 32, phase);
        }
        int rounds = 0;
        for (;;) {
            int v = (tid < 32) ? cloadi(bar + LEAF_BASE + tid * 32)
                               : 0x7fffffff;
#pragma unroll
            for (int off = 32; off > 0; off >>= 1)
                v = min(v, __shfl_xor(v, off));
            if (v >= phase) break;
            if (rounds < 8) __builtin_amdgcn_s_sleep(1);
            else            __builtin_amdgcn_s_sleep(4);
            if (++rounds > (1 << 20)) break;          // failsafe: no hang
        }
    }
    __syncthreads();
}

// ---------------------------------------------------------------------------
// gc1 A loader from f32 features. A[m=lane&15][k=quad*8 + c*32 + j].
// ---------------------------------------------------------------------------
__device__ __forceinline__ void load_a_feat(s16x8* a, const float* __restrict__ features,
                                            int m0, int lane, int quad) {
    const float* fr = features + (((size_t)(m0 + (lane & 15))) << 8) + quad * 8;
#pragma unroll
    for (int c = 0; c < 8; ++c) {
        float4 f0 = *reinterpret_cast<const float4*>(fr + c * 32);
        float4 f1 = *reinterpret_cast<const float4*>(fr + c * 32 + 4);
        s16x8 v;
        v[0] = (short)__bfloat16_as_ushort(__float2bfloat16(f0.x));
        v[1] = (short)__bfloat16_as_ushort(__float2bfloat16(f0.y));
        v[2] = (short)__bfloat16_as_ushort(__float2bfloat16(f0.z));
        v[3] = (short)__bfloat16_as_ushort(__float2bfloat16(f0.w));
        v[4] = (short)__bfloat16_as_ushort(__float2bfloat16(f1.x));
        v[5] = (short)__bfloat16_as_ushort(__float2bfloat16(f1.y));
        v[6] = (short)__bfloat16_as_ushort(__float2bfloat16(f1.z));
        v[7] = (short)__bfloat16_as_ushort(__float2bfloat16(f1.w));
        a[c] = v;
    }
}

// ---------------------------------------------------------------------------
// Partial MFMA accumulate over K-chunk range [C0,C1). c>=2 chunks need only
// pass-through cols of x_prev -> usable BEFORE the barrier wait (overlap).
// ---------------------------------------------------------------------------
template<int KT, int C0, int C1>
__device__ __forceinline__ void mm_acc(f32x4* acc, const unsigned short* xs,
                                       const unsigned short* __restrict__ Wt,
                                       int lane, int wave, int quad) {
    const short* xr = reinterpret_cast<const short*>(xs) + (lane & 15) * XSTR + quad * 8;
    s16x8 a[C1 - C0];
#pragma unroll
    for (int c = C0; c < C1; ++c)
        a[c - C0] = *reinterpret_cast<const s16x8*>(xr + c * 32);
    const short* wb = reinterpret_cast<const short*>(Wt);
#pragma unroll
    for (int tt = 0; tt < 3; ++tt) {
        const int t = wave * 3 + tt;
        const short* wp = wb + ((size_t)t * KT * 64 + lane) * 8;
#pragma unroll
        for (int c = C0; c < C1; ++c) {
            s16x8 b = *reinterpret_cast<const s16x8*>(wp + (size_t)c * 512);
            acc[tt] = __builtin_amdgcn_mfma_f32_16x16x32_bf16(a[c - C0], b, acc[tt], 0, 0, 0);
        }
    }
}

// ---------------------------------------------------------------------------
// Epilogue: n<64 -> bf16 sup (sc1); n>=64 -> EP transform into LDS.
// EP: 0 x=relu; 1 feat=(featG+relu)/2; 2 feat=(feat+relu)/2; 3 EP2+outFeat.
// ---------------------------------------------------------------------------
template<int EP>
__device__ __forceinline__ void mm_epilogue(
    const f32x4* acc, const float* __restrict__ bias,
    unsigned short* __restrict__ supW, unsigned short* xdst, float* featL,
    const float* __restrict__ featG, float* __restrict__ outFeat,
    int m0, int lane, int wave, int quad)
{
#pragma unroll
    for (int tt = 0; tt < 3; ++tt) {
        const int n = (wave * 3 + tt) * 16 + (lane & 15);
#pragma unroll
        for (int r = 0; r < 4; ++r) {
            const int m = quad * 4 + r;
            float v = acc[tt][r];
            if (n < 64) {
                cstoreh(&supW[(((size_t)(m0 + m)) << 6) + n],
                        __bfloat16_as_ushort(__float2bfloat16(v)));
            } else {
                v += bias[n];
                float x = fmaxf(v, 0.f);
                if constexpr (EP == 0) {
                    xdst[m * XSTR + n] = __bfloat16_as_ushort(__float2bfloat16(x));
                } else if constexpr (EP == 1) {
                    float f = (featG[(size_t)(m0 + m) * 256 + n] + x) * 0.5f;
                    featL[m * FFSTR + n] = f;
                    xdst[m * XSTR + n] = __bfloat16_as_ushort(__float2bfloat16(f));
                } else if constexpr (EP == 2) {
                    float f = (featL[m * FFSTR + n] + x) * 0.5f;
                    featL[m * FFSTR + n] = f;
                    xdst[m * XSTR + n] = __bfloat16_as_ushort(__float2bfloat16(f));
                } else {
                    float f = (featL[m * FFSTR + n] + x) * 0.5f;
                    featL[m * FFSTR + n] = f;
                    outFeat[(size_t)(m0 + m) * 192 + n] = f;
                }
            }
        }
    }
}

// ---------------------------------------------------------------------------
// Aggregation: wave's 4 rows interleaved, k-step 8 -> 32 cached bf16 gather
// loads in flight. Tails masked; &8191 keeps speculative loads in-bounds.
// ---------------------------------------------------------------------------
template<int EP>
__device__ __forceinline__ void agg_phase(
    const unsigned short* __restrict__ supR,
    const int* colsL, const int* cntL,
    const float* __restrict__ bias, unsigned short* xdst,
    float* featL, const float* __restrict__ featG,
    float* __restrict__ outFeat,
    int m0, int lane, int wave)
{
    const int base = wave * 4;
    int na[4];
#pragma unroll
    for (int rr = 0; rr < 4; ++rr) na[rr] = cntL[base + rr];
    int nmax = max(max(na[0], na[1]), max(na[2], na[3]));
    float s[4] = {0.f, 0.f, 0.f, 0.f};
    for (int k = 0; k < nmax; k += 8) {
        float v[32];
#pragma unroll
        for (int rr = 0; rr < 4; ++rr) {
            int4 c0 = *reinterpret_cast<const int4*>(colsL + (base + rr) * CAP + k);
            int4 c1 = *reinterpret_cast<const int4*>(colsL + (base + rr) * CAP + k + 4);
            v[rr * 8 + 0] = b2f(supR[((size_t)(c0.x & 8191) << 6) + lane]);
            v[rr * 8 + 1] = b2f(supR[((size_t)(c0.y & 8191) << 6) + lane]);
            v[rr * 8 + 2] = b2f(supR[((size_t)(c0.z & 8191) << 6) + lane]);
            v[rr * 8 + 3] = b2f(supR[((size_t)(c0.w & 8191) << 6) + lane]);
            v[rr * 8 + 4] = b2f(supR[((size_t)(c1.x & 8191) << 6) + lane]);
            v[rr * 8 + 5] = b2f(supR[((size_t)(c1.y & 8191) << 6) + lane]);
            v[rr * 8 + 6] = b2f(supR[((size_t)(c1.z & 8191) << 6) + lane]);
            v[rr * 8 + 7] = b2f(supR[((size_t)(c1.w & 8191) << 6) + lane]);
        }
#pragma unroll
        for (int rr = 0; rr < 4; ++rr) {
#pragma unroll
            for (int j = 0; j < 8; ++j)
                s[rr] += (k + j < na[rr]) ? v[rr * 8 + j] : 0.f;
        }
    }
#pragma unroll
    for (int rr = 0; rr < 4; ++rr) {
        const int lrow = base + rr;
        const int row = m0 + lrow;
        float vv = s[rr] * 0.03125f + bias[lane];
        float x = fmaxf(vv, 0.f);
        if constexpr (EP == 0) {
            xdst[lrow * XSTR + lane] = __bfloat16_as_ushort(__float2bfloat16(x));
        } else if constexpr (EP == 1) {
            float f = (featG[(size_t)row * 256 + lane] + x) * 0.5f;
            featL[lrow * FFSTR + lane] = f;
            xdst[lrow * XSTR + lane] = __bfloat16_as_ushort(__float2bfloat16(f));
        } else if constexpr (EP == 2) {
            float f = (featL[lrow * FFSTR + lane] + x) * 0.5f;
            featL[lrow * FFSTR + lane] = f;
            xdst[lrow * XSTR + lane] = __bfloat16_as_ushort(__float2bfloat16(f));
        } else {
            float f = (featL[lrow * FFSTR + lane] + x) * 0.5f;
            featL[lrow * FFSTR + lane] = f;
            outFeat[(size_t)row * 192 + lane] = f;
        }
    }
}

// ---------------------------------------------------------------------------
// One layer step (gc2..gc13): hi-mm (chunks 2..5) overlaps the wait; agg of
// the previous layer; lo-mm (chunks 0,1) + epilogue; arrive.
// ---------------------------------------------------------------------------
template<int EPprev, int EPcur>
__device__ __forceinline__ void layer_step(
    int* bar, int ph,
    unsigned short* xsPrev, unsigned short* xsCur,
    const unsigned short* __restrict__ supPrev, unsigned short* __restrict__ supCur,
    const unsigned short* __restrict__ Wt,
    const float* __restrict__ biasPrev, const float* __restrict__ biasCur,
    float* featL, const float* __restrict__ featG, float* __restrict__ outFeat,
    const int* colsL, const int* cntL,
    int m0, int lane, int wave, int quad)
{
    f32x4 acc[3] = {};
    mm_acc<6, 2, 6>(acc, xsPrev, Wt, lane, wave, quad);
    gbar_wait(bar, ph);
    agg_phase<EPprev>(supPrev, colsL, cntL, biasPrev, xsPrev, featL, featG,
                      outFeat, m0, lane, wave);
    __syncthreads();
    mm_acc<6, 0, 2>(acc, xsPrev, Wt, lane, wave, quad);
    mm_epilogue<EPcur>(acc, biasCur, supCur, xsCur, featL, featG, outFeat,
                       m0, lane, wave, quad);
    gbar_arrive(bar, ph + 1);
}

// ---------------------------------------------------------------------------
// Persistent layers kernel. CSR + weights come pre-built from 'prep' (plain
// cached loads; dispatch boundary = coherence). LDS ~33KB -> 2 blocks/CU.
// ---------------------------------------------------------------------------
__global__ __launch_bounds__(256, 2) void fused_layers(
    const float* __restrict__ features,
    const int* __restrict__ cnt, const int* __restrict__ cols,
    const unsigned short* __restrict__ Wt1, const unsigned short* __restrict__ WtM,
    const float* __restrict__ b1, const float* __restrict__ bm,
    const float* __restrict__ Wout, const float* __restrict__ bout,
    unsigned short* __restrict__ supBase, float* __restrict__ sup3,
    float* __restrict__ out, float* __restrict__ outFeat,
    int* __restrict__ bar)
{
    __shared__ unsigned short xsA[16 * XSTR];
    __shared__ unsigned short xsB[16 * XSTR];
    __shared__ float featL[16 * FFSTR];
    __shared__ int colsL[16 * CAP];
    __shared__ int cntL[16];

    const int tid = threadIdx.x;
    const int lane = tid & 63;
    const int wave = tid >> 6;
    const int quad = lane >> 4;
    const int m0 = blockIdx.x * 16;
    int ph = 0;

    // ---- load this block's CSR rows (coalesced, one shot)
    for (int i = tid; i < 16 * (CAP / 4); i += 256) {
        int r = i >> 5;
        int g = (i & 31) << 2;
        *reinterpret_cast<int4*>(&colsL[r * CAP + g]) =
            *reinterpret_cast<const int4*>(cols + (size_t)(m0 + r) * CAP + g);
    }
    if (tid < 16) {
        int nn = cnt[m0 + tid];
        cntL[tid] = nn > CAP ? CAP : nn;
    }
    __syncthreads();

    // ---- gc1: monolithic KT=8 from features, EP0 -> sup[0], xsA
    {
        s16x8 a8[8];
        load_a_feat(a8, features, m0, lane, quad);
        f32x4 acc[3] = {};
        const short* wb = reinterpret_cast<const short*>(Wt1);
#pragma unroll
        for (int tt = 0; tt < 3; ++tt) {
            const int t = wave * 3 + tt;
            const short* wp = wb + ((size_t)t * 8 * 64 + lane) * 8;
#pragma unroll
            for (int c = 0; c < 8; ++c) {
                s16x8 b = *reinterpret_cast<const s16x8*>(wp + (size_t)c * 512);
                acc[tt] = __builtin_amdgcn_mfma_f32_16x16x32_bf16(a8[c], b, acc[tt], 0, 0, 0);
            }
        }
        mm_epilogue<0>(acc, b1, supBase, xsA, featL, features, outFeat,
                       m0, lane, wave, quad);
    }
    gbar_arrive(bar, ++ph);                // ph=1

    // ---- l=2 (gc2, Wm[0], EP1); agg of gc1 (EP0)
    layer_step<0, 1>(bar, ph, xsA, xsB, supBase, supBase + SUPSZ,
                     WtM, b1, bm, featL, features, outFeat,
                     colsL, cntL, m0, lane, wave, quad);
    ++ph;                                  // ph=2
    // ---- l=3 (gc3, Wm[1], EP0); agg of gc2 (EP1)
    layer_step<1, 0>(bar, ph, xsB, xsA, supBase + SUPSZ, supBase + 2 * SUPSZ,
                     WtM + 36864, bm, bm + 192, featL, features, outFeat,
                     colsL, cntL, m0, lane, wave, quad);
    ++ph;                                  // ph=3
    // ---- l=4 (gc4, Wm[2], EP2); agg of gc3 (EP0)
    layer_step<0, 2>(bar, ph, xsA, xsB, supBase + 2 * SUPSZ, supBase + 3 * SUPSZ,
                     WtM + 2 * 36864, bm + 192, bm + 2 * 192, featL, features,
                     outFeat, colsL, cntL, m0, lane, wave, quad);
    ++ph;                                  // ph=4

    // ---- l=5..12: pairs (odd EP0 after prev EP2; even EP2 after prev EP0)
    for (int p = 1; p <= 4; ++p) {
        const int l = 3 + 2 * p;           // 5,7,9,11
        layer_step<2, 0>(bar, ph, xsB, xsA,
                         supBase + (size_t)(l - 2) * SUPSZ,
                         supBase + (size_t)(l - 1) * SUPSZ,
                         WtM + (size_t)(l - 2) * 36864,
                         bm + (l - 3) * 192, bm + (l - 2) * 192,
                         featL, features, outFeat, colsL, cntL,
                         m0, lane, wave, quad);
        ++ph;
        const int l2 = l + 1;              // 6,8,10,12
        layer_step<0, 2>(bar, ph, xsA, xsB,
                         supBase + (size_t)(l2 - 2) * SUPSZ,
                         supBase + (size_t)(l2 - 1) * SUPSZ,
                         WtM + (size_t)(l2 - 2) * 36864,
                         bm + (l2 - 3) * 192, bm + (l2 - 2) * 192,
                         featL, features, outFeat, colsL, cntL,
                         m0, lane, wave, quad);
        ++ph;
    }                                      // ph=12

    // ---- l=13 (gc13, Wm[11], EP3); agg of gc12 (EP2)
    layer_step<2, 3>(bar, ph, xsB, xsA, supBase + 11 * SUPSZ, supBase + 12 * SUPSZ,
                     WtM + 11 * 36864, bm + 10 * 192, bm + 11 * 192,
                     featL, features, outFeat, colsL, cntL, m0, lane, wave, quad);
    ++ph;                                  // ph=13

    // ---- gc14 matmul, hi part (kk 64..191) overlaps the wait
    float s3[4][3];
#pragma unroll
    for (int rr = 0; rr < 4; ++rr) { s3[rr][0] = 0.f; s3[rr][1] = 0.f; s3[rr][2] = 0.f; }
#pragma unroll
    for (int rr = 0; rr < 4; ++rr) {
        const int lrow = wave * 4 + rr;
#pragma unroll
        for (int pp = 1; pp < 3; ++pp) {
            int kk = pp * 64 + lane;
            float f = featL[lrow * FFSTR + kk];
            s3[rr][0] += f * Wout[kk * 3 + 0];
            s3[rr][1] += f * Wout[kk * 3 + 1];
            s3[rr][2] += f * Wout[kk * 3 + 2];
        }
    }
    gbar_wait(bar, ph);                    // sup[12] visible
    agg_phase<3>(supBase + (size_t)12 * SUPSZ, colsL, cntL, bm + 11 * 192,
                 xsA, featL, features, outFeat, m0, lane, wave);
    __syncthreads();
#pragma unroll
    for (int rr = 0; rr < 4; ++rr) {
        const int lrow = wave * 4 + rr;
        float f = featL[lrow * FFSTR + lane];
        float s0 = s3[rr][0] + f * Wout[lane * 3 + 0];
        float s1 = s3[rr][1] + f * Wout[lane * 3 + 1];
        float s2 = s3[rr][2] + f * Wout[lane * 3 + 2];
#pragma unroll
        for (int off = 32; off > 0; off >>= 1) {
            s0 += __shfl_down(s0, off);
            s1 += __shfl_down(s1, off);
            s2 += __shfl_down(s2, off);
        }
        if (lane == 0) {
            float* sp = sup3 + (((size_t)(m0 + lrow)) << 2);
            cstoref(sp + 0, s0);
            cstoref(sp + 1, s1);
            cstoref(sp + 2, s2);
        }
    }
    gbar_arrive(bar, ++ph);                // ph=14
    gbar_wait(bar, ph);

    // ---- gc14 aggregation: side_len = 2; 16 threads per row (cached loads)
    {
        const int lrow = tid >> 4;
        const int row = m0 + lrow;
        const int sub = tid & 15;
        int n = cntL[lrow];
        const int* cl = colsL + lrow * CAP;
        float s0 = 0.f, s1 = 0.f;
        for (int k = sub; k < n; k += 16) {
            int j = cl[k];
            s0 += sup3[((size_t)j << 2) + 0];
            s1 += sup3[((size_t)j << 2) + 1];
        }
#pragma unroll
        for (int off = 8; off > 0; off >>= 1) {
            s0 += __shfl_down(s0, off, 16);
            s1 += __shfl_down(s1, off, 16);
        }
        if (sub == 0) {
            float* op = out + (size_t)row * 3;
            op[0] = s0 * 0.03125f + bout[0];
            op[1] = s1 * 0.03125f + bout[1];
            op[2] = sup3[((size_t)row << 2) + 2] + bout[2];
        }
    }
}

extern "C" void kernel_launch(void* const* d_in, const int* in_sizes, int n_in,
                              void* d_out, int out_size, void* d_ws, size_t ws_size,
                              hipStream_t stream) {
    const float* features = (const float*)d_in[0];
    const unsigned int* adj = (const unsigned int*)d_in[1];
    const float* W1 = (const float*)d_in[2];
    const float* b1 = (const float*)d_in[3];
    const float* Wm = (const float*)d_in[4];
    const float* bm = (const float*)d_in[5];
    const float* Wo = (const float*)d_in[6];
    const float* bo = (const float*)d_in[7];
    float* out = (float*)d_out;
    float* outFeat = out + (size_t)N_NODES * 3;

    char* w = (char*)d_ws;
    int* bar = (int*)(w);                                     // 128 KB flags
    int* cnt = (int*)(w + 131072);                            // 32 KB -> 163840
    int* cols = (int*)(w + 163840);                           // 4 MB -> 4,358,144
    unsigned short* supBase = (unsigned short*)(w + 4358144); // 13 MB -> 17,989,632
    float* sup3 = (float*)(w + 17989632);                     // 128 KB -> 18,120,704
    unsigned short* Wt1 = (unsigned short*)(w + 18120704);    // 96 KB -> 18,219,008
    unsigned short* WtM = (unsigned short*)(w + 18219008);    // 864 KB -> 19,103,744

    hipMemsetAsync(bar, 0, 131072, stream);
    prep<<<2288, 256, 0, stream>>>(adj, W1, Wm, cnt, cols, Wt1, WtM);
    fused_layers<<<NBLK, 256, 0, stream>>>(features, cnt, cols, Wt1, WtM, b1, bm,
                                           Wo, bo, supBase, sup3, out, outFeat, bar);

    (void)in_sizes; (void)n_in; (void)out_size; (void)ws_size;
}